// Round 2
// baseline (112.137 us; speedup 1.0000x reference)
//
#include <hip/hip_runtime.h>

#define Bn 8
#define Hn 128
#define Wn 128
#define Cn 64
#define NHEADS 4
#define Dn 16
#define NS 26           // 5*5 neighbors + self
#define TILE 16
#define HALO 20         // TILE + 2*2
#define NTHR 512

// 512 threads = 8 waves per block. Threads 0-255 handle heads {0,1} (buf 0),
// threads 256-511 handle heads {2,3} (buf 1). Two k-halo buffers live at once
// -> 52.5 KB LDS, 2 blocks/CU resident -> 16 waves/CU (2x the R1 occupancy).
__global__ __launch_bounds__(NTHR, 2)
void local_attn_fused(const float* __restrict__ mainp,
                      const float* __restrict__ refp,
                      const float* __restrict__ Wm,
                      const float* __restrict__ Wr,
                      float* __restrict__ out)
{
    // [buf][d-quad plane][row][col(+1 pad)] ; pad breaks row-stride bank aliasing
    __shared__ __align__(16) float4 sK[2][4][HALO][HALO + 1];

    const int tid  = threadIdx.x;
    const int px   = tid & 255;
    const int hgrp = tid >> 8;          // 0 or 1
    const int tx   = px & (TILE - 1);
    const int ty   = px >> 4;
    const int b    = blockIdx.z;
    const int y0   = blockIdx.y * TILE;
    const int x0   = blockIdx.x * TILE;

    const float4* mp4 =
        (const float4*)(mainp + (((size_t)b * Hn + (y0 + ty)) * Wn + (x0 + tx)) * Cn);

    float attn[NS];
#pragma unroll
    for (int i = 0; i < NS; ++i) attn[i] = 0.f;

    for (int iter = 0; iter < 2; ++iter) {
        const int hA = iter;        // head staged into buf 0
        const int hB = 2 + iter;    // head staged into buf 1

        __syncthreads();            // protect buffers from previous readers

        // ---- k projection: 400 halo pixels, BOTH active heads per task ----
        if (tid < HALO * HALO) {
            const int hr = tid / HALO;
            const int hc = tid - hr * HALO;
            const int gy = y0 - 2 + hr;
            const int gx = x0 - 2 + hc;
            float kvA[Dn], kvB[Dn];
#pragma unroll
            for (int d = 0; d < Dn; ++d) { kvA[d] = 0.f; kvB[d] = 0.f; }
            if ((unsigned)gy < (unsigned)Hn && (unsigned)gx < (unsigned)Wn) {
                const float4* rp4 =
                    (const float4*)(refp + (((size_t)b * Hn + gy) * Wn + gx) * Cn);
                const float* wA = Wr + hA * Cn * Dn;   // wave-uniform -> s_load
                const float* wB = Wr + hB * Cn * Dn;
#pragma unroll
                for (int c4 = 0; c4 < Cn / 4; ++c4) {
                    const float4 rv = rp4[c4];
                    const float rj[4] = {rv.x, rv.y, rv.z, rv.w};
#pragma unroll
                    for (int j = 0; j < 4; ++j) {
                        const float* wa = wA + (c4 * 4 + j) * Dn;
                        const float* wb = wB + (c4 * 4 + j) * Dn;
#pragma unroll
                        for (int d = 0; d < Dn; ++d) {
                            kvA[d] = fmaf(rj[j], wa[d], kvA[d]);
                            kvB[d] = fmaf(rj[j], wb[d], kvB[d]);
                        }
                    }
                }
            }
            sK[0][0][hr][hc] = make_float4(kvA[0],  kvA[1],  kvA[2],  kvA[3]);
            sK[0][1][hr][hc] = make_float4(kvA[4],  kvA[5],  kvA[6],  kvA[7]);
            sK[0][2][hr][hc] = make_float4(kvA[8],  kvA[9],  kvA[10], kvA[11]);
            sK[0][3][hr][hc] = make_float4(kvA[12], kvA[13], kvA[14], kvA[15]);
            sK[1][0][hr][hc] = make_float4(kvB[0],  kvB[1],  kvB[2],  kvB[3]);
            sK[1][1][hr][hc] = make_float4(kvB[4],  kvB[5],  kvB[6],  kvB[7]);
            sK[1][2][hr][hc] = make_float4(kvB[8],  kvB[9],  kvB[10], kvB[11]);
            sK[1][3][hr][hc] = make_float4(kvB[12], kvB[13], kvB[14], kvB[15]);
        }

        // ---- q projection for my pixel, my head this iter ----
        const int myhead = hgrp * 2 + iter;
        const float* wmh = Wm + myhead * Cn * Dn;
        float q[Dn];
#pragma unroll
        for (int d = 0; d < Dn; ++d) q[d] = 0.f;
#pragma unroll
        for (int c4 = 0; c4 < Cn / 4; ++c4) {
            const float4 mv = mp4[c4];
            const float mj[4] = {mv.x, mv.y, mv.z, mv.w};
#pragma unroll
            for (int j = 0; j < 4; ++j) {
                const float* wrow = wmh + (c4 * 4 + j) * Dn;
#pragma unroll
                for (int d = 0; d < Dn; ++d)
                    q[d] = fmaf(mj[j], wrow[d], q[d]);
            }
        }

        __syncthreads();

        // ---- 25 neighbor scores + self score ----
        float sc[NS];
#pragma unroll
        for (int di = 0; di < 5; ++di) {
#pragma unroll
            for (int dj = 0; dj < 5; ++dj) {
                const int r = ty + di;
                const int c = tx + dj;
                const float4 k0 = sK[hgrp][0][r][c];
                const float4 k1 = sK[hgrp][1][r][c];
                const float4 k2 = sK[hgrp][2][r][c];
                const float4 k3 = sK[hgrp][3][r][c];
                float s;
                s = q[0] * k0.x;
                s = fmaf(q[1],  k0.y, s);
                s = fmaf(q[2],  k0.z, s);
                s = fmaf(q[3],  k0.w, s);
                s = fmaf(q[4],  k1.x, s);
                s = fmaf(q[5],  k1.y, s);
                s = fmaf(q[6],  k1.z, s);
                s = fmaf(q[7],  k1.w, s);
                s = fmaf(q[8],  k2.x, s);
                s = fmaf(q[9],  k2.y, s);
                s = fmaf(q[10], k2.z, s);
                s = fmaf(q[11], k2.w, s);
                s = fmaf(q[12], k3.x, s);
                s = fmaf(q[13], k3.y, s);
                s = fmaf(q[14], k3.z, s);
                s = fmaf(q[15], k3.w, s);
                sc[di * 5 + dj] = s;
            }
        }
        {
            float s = q[0] * q[0];
#pragma unroll
            for (int d = 1; d < Dn; ++d) s = fmaf(q[d], q[d], s);
            sc[25] = s;
        }

        // ---- per-head softmax, accumulate ----
        float mx = sc[0];
#pragma unroll
        for (int i = 1; i < NS; ++i) mx = fmaxf(mx, sc[i]);
        float ssum = 0.f;
#pragma unroll
        for (int i = 0; i < NS; ++i) { sc[i] = __expf(sc[i] - mx); ssum += sc[i]; }
        const float inv = 1.0f / ssum;
#pragma unroll
        for (int i = 0; i < NS; ++i) attn[i] = fmaf(sc[i], inv, attn[i]);
    }

    // ---- combine head-groups via LDS, then coalesced store ----
    __syncthreads();                       // all score reads done
    float* sO = (float*)sK;                // reuse buf 0 (26.6 KB needed)
    if (hgrp == 1) {
#pragma unroll
        for (int i = 0; i < NS; ++i) sO[px * NS + i] = attn[i];
    }
    __syncthreads();
    if (hgrp == 0) {
#pragma unroll
        for (int i = 0; i < NS; ++i)
            sO[px * NS + i] = (sO[px * NS + i] + attn[i]) * 0.25f;
    }
    __syncthreads();
    const int rowlen = TILE * NS;          // 416 contiguous floats per tile row
    for (int idx = tid; idx < TILE * rowlen; idx += NTHR) {
        const int row = idx / rowlen;
        const int col = idx - row * rowlen;
        out[(((size_t)b * Hn + (y0 + row)) * Wn + x0) * NS + col] = sO[idx];
    }
}

extern "C" void kernel_launch(void* const* d_in, const int* in_sizes, int n_in,
                              void* d_out, int out_size, void* d_ws, size_t ws_size,
                              hipStream_t stream) {
    (void)in_sizes; (void)n_in; (void)d_ws; (void)ws_size; (void)out_size;
    const float* mainp = (const float*)d_in[0];
    const float* refp  = (const float*)d_in[1];
    const float* Wm    = (const float*)d_in[2];
    const float* Wr    = (const float*)d_in[3];
    float* out = (float*)d_out;
    dim3 grid(Wn / TILE, Hn / TILE, Bn);   // 8 x 8 x 8 = 512 blocks x 8 waves
    local_attn_fused<<<grid, NTHR, 0, stream>>>(mainp, refp, Wm, Wr, out);
}

// Round 3
// 77.669 us; speedup vs baseline: 1.4438x; 1.4438x over previous
//
#include <hip/hip_runtime.h>

#define Bn 8
#define Hn 128
#define Wn 128
#define Cn 64
#define Dn 16
#define NS 26            // 5*5 neighbors + self
#define TILE 8           // 8x8 pixel tile per block
#define HALO 12          // TILE + 2*2
#define NHALO (HALO * HALO)   // 144
#define PXW 36           // u32 words per halo px: 4 heads * 8 + 4 pad (bank rotation)

// round-to-nearest-even f32 -> bf16 (bits), branchless
__device__ __forceinline__ unsigned int rnbf16(float f) {
    unsigned int x = __float_as_uint(f);
    return (x + 0x7fffu + ((x >> 16) & 1u)) >> 16;
}
__device__ __forceinline__ float bflo(unsigned int u) { return __uint_as_float(u << 16); }
__device__ __forceinline__ float bfhi(unsigned int u) { return __uint_as_float(u & 0xffff0000u); }

// 256 threads = 64 pixels x 4 waves; wave w owns head w everywhere
// (weight pointers wave-uniform -> s_load; zero VMEM traffic for W).
// LDS: 20736 B -> >=3 blocks/CU even under a 64-KB residency regime.
__global__ __launch_bounds__(256, 4)
void local_attn_fused(const float* __restrict__ mainp,
                      const float* __restrict__ refp,
                      const float* __restrict__ Wm,
                      const float* __restrict__ Wr,
                      float* __restrict__ out)
{
    __shared__ unsigned int sK[NHALO * PXW];   // bf16x2-packed k, 20736 B

    const int tid  = threadIdx.x;
    const int lane = tid & 63;
    const int wv   = tid >> 6;
    const int head = __builtin_amdgcn_readfirstlane(wv);   // SGPR head id
    const int b    = blockIdx.z;
    const int y0   = blockIdx.y * TILE;
    const int x0   = blockIdx.x * TILE;

    // ---- stage k for my head over the 12x12 halo (zero-padded SAME) ----
    const float* wrh = Wr + head * (Cn * Dn);              // scalar -> s_load
    for (int p = lane; p < NHALO; p += 64) {
        const int hr = p / HALO;
        const int hc = p - hr * HALO;
        const int gy = y0 - 2 + hr;
        const int gx = x0 - 2 + hc;
        float kv[Dn];
#pragma unroll
        for (int d = 0; d < Dn; ++d) kv[d] = 0.f;
        if ((unsigned)gy < (unsigned)Hn && (unsigned)gx < (unsigned)Wn) {
            const float4* rp4 =
                (const float4*)(refp + (((size_t)b * Hn + gy) * Wn + gx) * Cn);
#pragma unroll
            for (int c4 = 0; c4 < Cn / 4; ++c4) {
                const float4 rv = rp4[c4];
                const float rj[4] = {rv.x, rv.y, rv.z, rv.w};
#pragma unroll
                for (int j = 0; j < 4; ++j) {
                    const float* wrow = wrh + (c4 * 4 + j) * Dn;
#pragma unroll
                    for (int d = 0; d < Dn; ++d)
                        kv[d] = fmaf(rj[j], wrow[d], kv[d]);
                }
            }
        }
        unsigned int pk[8];
#pragma unroll
        for (int j = 0; j < 8; ++j)
            pk[j] = rnbf16(kv[2 * j]) | (rnbf16(kv[2 * j + 1]) << 16);
        unsigned int* dst = sK + p * PXW + head * 8;       // 16B-aligned
        *(uint4*)(dst)     = make_uint4(pk[0], pk[1], pk[2], pk[3]);
        *(uint4*)(dst + 4) = make_uint4(pk[4], pk[5], pk[6], pk[7]);
    }

    // ---- q projection for my pixel, my head (pre-barrier: overlaps staging) ----
    const int pr = lane >> 3;
    const int pc = lane & 7;
    const float* wmh = Wm + head * (Cn * Dn);              // scalar -> s_load
    const float4* mp4 =
        (const float4*)(mainp + (((size_t)b * Hn + (y0 + pr)) * Wn + (x0 + pc)) * Cn);
    float q[Dn];
#pragma unroll
    for (int d = 0; d < Dn; ++d) q[d] = 0.f;
#pragma unroll
    for (int c4 = 0; c4 < Cn / 4; ++c4) {
        const float4 mv = mp4[c4];
        const float mj[4] = {mv.x, mv.y, mv.z, mv.w};
#pragma unroll
        for (int j = 0; j < 4; ++j) {
            const float* wrow = wmh + (c4 * 4 + j) * Dn;
#pragma unroll
            for (int d = 0; d < Dn; ++d)
                q[d] = fmaf(mj[j], wrow[d], q[d]);
        }
    }

    __syncthreads();

    // ---- 25 neighbor scores (bf16 k from LDS) + f32 self score ----
    float sc[NS];
#pragma unroll
    for (int di = 0; di < 5; ++di) {
#pragma unroll
        for (int dj = 0; dj < 5; ++dj) {
            const int h = (pr + di) * HALO + (pc + dj);
            const unsigned int* src = sK + h * PXW + head * 8;
            const uint4 ka = *(const uint4*)(src);
            const uint4 kb = *(const uint4*)(src + 4);
            float s;
            s = q[0] * bflo(ka.x);
            s = fmaf(q[1],  bfhi(ka.x), s);
            s = fmaf(q[2],  bflo(ka.y), s);
            s = fmaf(q[3],  bfhi(ka.y), s);
            s = fmaf(q[4],  bflo(ka.z), s);
            s = fmaf(q[5],  bfhi(ka.z), s);
            s = fmaf(q[6],  bflo(ka.w), s);
            s = fmaf(q[7],  bfhi(ka.w), s);
            s = fmaf(q[8],  bflo(kb.x), s);
            s = fmaf(q[9],  bfhi(kb.x), s);
            s = fmaf(q[10], bflo(kb.y), s);
            s = fmaf(q[11], bfhi(kb.y), s);
            s = fmaf(q[12], bflo(kb.z), s);
            s = fmaf(q[13], bfhi(kb.z), s);
            s = fmaf(q[14], bflo(kb.w), s);
            s = fmaf(q[15], bfhi(kb.w), s);
            sc[di * 5 + dj] = s;
        }
    }
    {
        float s = q[0] * q[0];
#pragma unroll
        for (int d = 1; d < Dn; ++d) s = fmaf(q[d], q[d], s);
        sc[25] = s;
    }

    // ---- per-head softmax in registers ----
    float mx = sc[0];
#pragma unroll
    for (int i = 1; i < NS; ++i) mx = fmaxf(mx, sc[i]);
    float ssum = 0.f;
#pragma unroll
    for (int i = 0; i < NS; ++i) { sc[i] = __expf(sc[i] - mx); ssum += sc[i]; }
    const float inv = 1.0f / ssum;
#pragma unroll
    for (int i = 0; i < NS; ++i) sc[i] *= inv;

    // ---- head-mean via LDS (reuse sK as bf16 [4][64][27]) ----
    __syncthreads();                         // all k reads complete
    unsigned short* sA = (unsigned short*)sK;
    {
        unsigned short* myrow = sA + (wv * 64 + lane) * 27;
#pragma unroll
        for (int i = 0; i < NS; ++i) myrow[i] = (unsigned short)rnbf16(sc[i]);
    }
    __syncthreads();

    // ---- combine 4 heads + coalesced store (208-float contiguous runs) ----
    const size_t obase = (((size_t)b * Hn + y0) * Wn + x0) * NS;
    for (int idx = tid; idx < TILE * TILE * NS; idx += 256) {
        const int r  = idx / (TILE * NS);
        const int t  = idx - r * (TILE * NS);
        const int c  = t / NS;
        const int i  = t - c * NS;
        const int px = r * TILE + c;
        float acc;
        acc  = __uint_as_float(((unsigned int)sA[(0 * 64 + px) * 27 + i]) << 16);
        acc += __uint_as_float(((unsigned int)sA[(1 * 64 + px) * 27 + i]) << 16);
        acc += __uint_as_float(((unsigned int)sA[(2 * 64 + px) * 27 + i]) << 16);
        acc += __uint_as_float(((unsigned int)sA[(3 * 64 + px) * 27 + i]) << 16);
        out[obase + (size_t)r * (Wn * NS) + t] = 0.25f * acc;
    }
}

extern "C" void kernel_launch(void* const* d_in, const int* in_sizes, int n_in,
                              void* d_out, int out_size, void* d_ws, size_t ws_size,
                              hipStream_t stream) {
    (void)in_sizes; (void)n_in; (void)d_ws; (void)ws_size; (void)out_size;
    const float* mainp = (const float*)d_in[0];
    const float* refp  = (const float*)d_in[1];
    const float* Wm    = (const float*)d_in[2];
    const float* Wr    = (const float*)d_in[3];
    float* out = (float*)d_out;
    dim3 grid(Wn / TILE, Hn / TILE, Bn);   // 16 x 16 x 8 = 2048 blocks
    local_attn_fused<<<grid, 256, 0, stream>>>(mainp, refp, Wm, Wr, out);
}

// Round 4
// 69.794 us; speedup vs baseline: 1.6067x; 1.1128x over previous
//
#include <hip/hip_runtime.h>

#define Bn 8
#define Hn 128
#define Wn 128
#define Cn 64
#define Dn 16
#define NS 26            // 5*5 neighbors + self
#define TILE 8           // 8x8 pixel tile per block
#define HALO 12          // TILE + 2*2
#define NHALO (HALO * HALO)   // 144
#define PXW 36           // u32 words per halo px: 4 heads * 8 + 4 pad

typedef _Float16 h2 __attribute__((ext_vector_type(2)));

__device__ __forceinline__ unsigned int pkf16(float a, float b) {
    return __builtin_bit_cast(unsigned int, __builtin_amdgcn_cvt_pkrtz(a, b));
}
__device__ __forceinline__ float dot2(unsigned int a, unsigned int b, float c) {
    return __builtin_amdgcn_fdot2(__builtin_bit_cast(h2, a),
                                  __builtin_bit_cast(h2, b), c, false);
}

// ---- pre-pass: pack W into c-pair-major f16x2 so the main kernel can
// s_load one u32 = one dot2 operand.  wp[t][h][m][d], m = c/2 pair idx.
__global__ void pack_weights(const float* __restrict__ Wm,
                             const float* __restrict__ Wr,
                             unsigned int* __restrict__ wp) {
    const int idx = blockIdx.x * 256 + threadIdx.x;    // 4096 total
    if (idx < 2 * 4 * 32 * Dn) {
        const int t = idx >> 11;
        const int r = idx & 2047;
        const int h = r >> 9;
        const int m = (r >> 4) & 31;
        const int d = r & 15;
        const float* W = t ? Wr : Wm;
        const float a = W[h * (Cn * Dn) + (2 * m) * Dn + d];
        const float b = W[h * (Cn * Dn) + (2 * m + 1) * Dn + d];
        wp[idx] = pkf16(a, b);
    }
}

// 256 threads = 64 pixels x 4 waves; wave w owns head w (weight reads
// wave-uniform -> s_load; dot2 takes the SGPR operand directly).
__global__ __launch_bounds__(256, 4)
void local_attn_fused(const float* __restrict__ mainp,
                      const float* __restrict__ refp,
                      const unsigned int* __restrict__ wp,
                      float* __restrict__ out)
{
    __shared__ unsigned int sK[NHALO * PXW];   // f16x2-packed k, 20736 B

    const int tid  = threadIdx.x;
    const int lane = tid & 63;
    const int wv   = tid >> 6;
    const int head = __builtin_amdgcn_readfirstlane(wv);
    const int b    = blockIdx.z;
    const int y0   = blockIdx.y * TILE;
    const int x0   = blockIdx.x * TILE;

    const unsigned int* wmh = wp + head * (32 * Dn);            // main W, packed
    const unsigned int* wrh = wp + 2048 + head * (32 * Dn);     // ref W, packed

    // ---- stage k for my head over the 12x12 halo (zero-padded SAME) ----
    for (int p = lane; p < NHALO; p += 64) {
        const int hr = p / HALO;
        const int hc = p - hr * HALO;
        const int gy = y0 - 2 + hr;
        const int gx = x0 - 2 + hc;
        float acc[Dn];
#pragma unroll
        for (int d = 0; d < Dn; ++d) acc[d] = 0.f;
        if ((unsigned)gy < (unsigned)Hn && (unsigned)gx < (unsigned)Wn) {
            const float4* rp4 =
                (const float4*)(refp + (((size_t)b * Hn + gy) * Wn + gx) * Cn);
#pragma unroll
            for (int c4 = 0; c4 < Cn / 4; ++c4) {
                const float4 rv = rp4[c4];
                const unsigned int r01 = pkf16(rv.x, rv.y);
                const unsigned int r23 = pkf16(rv.z, rv.w);
                const unsigned int* w0 = wrh + (2 * c4) * Dn;
                const unsigned int* w1 = wrh + (2 * c4 + 1) * Dn;
#pragma unroll
                for (int d = 0; d < Dn; ++d) acc[d] = dot2(r01, w0[d], acc[d]);
#pragma unroll
                for (int d = 0; d < Dn; ++d) acc[d] = dot2(r23, w1[d], acc[d]);
            }
        }
        unsigned int pk[8];
#pragma unroll
        for (int j = 0; j < 8; ++j) pk[j] = pkf16(acc[2 * j], acc[2 * j + 1]);
        unsigned int* dst = sK + p * PXW + head * 8;   // 16B-aligned
        *(uint4*)(dst)     = make_uint4(pk[0], pk[1], pk[2], pk[3]);
        *(uint4*)(dst + 4) = make_uint4(pk[4], pk[5], pk[6], pk[7]);
    }

    // ---- q projection (f32 accum; overlaps staging, pre-barrier) ----
    const int pr = lane >> 3;
    const int pc = lane & 7;
    const float4* mp4 =
        (const float4*)(mainp + (((size_t)b * Hn + (y0 + pr)) * Wn + (x0 + pc)) * Cn);
    float q[Dn];
#pragma unroll
    for (int d = 0; d < Dn; ++d) q[d] = 0.f;
#pragma unroll
    for (int c4 = 0; c4 < Cn / 4; ++c4) {
        const float4 mv = mp4[c4];
        const unsigned int m01 = pkf16(mv.x, mv.y);
        const unsigned int m23 = pkf16(mv.z, mv.w);
        const unsigned int* w0 = wmh + (2 * c4) * Dn;
        const unsigned int* w1 = wmh + (2 * c4 + 1) * Dn;
#pragma unroll
        for (int d = 0; d < Dn; ++d) q[d] = dot2(m01, w0[d], q[d]);
#pragma unroll
        for (int d = 0; d < Dn; ++d) q[d] = dot2(m23, w1[d], q[d]);
    }
    // pack q for the score phase
    unsigned int qh[8];
#pragma unroll
    for (int j = 0; j < 8; ++j) qh[j] = pkf16(q[2 * j], q[2 * j + 1]);

    __syncthreads();

    // ---- 25 neighbor scores (packed-f16 dot2) + exact f32 self score ----
    float sc[NS];
#pragma unroll
    for (int di = 0; di < 5; ++di) {
#pragma unroll
        for (int dj = 0; dj < 5; ++dj) {
            const int h = (pr + di) * HALO + (pc + dj);
            const unsigned int* src = sK + h * PXW + head * 8;
            const uint4 ka = *(const uint4*)(src);
            const uint4 kb = *(const uint4*)(src + 4);
            float s;
            s = dot2(qh[0], ka.x, 0.f);
            s = dot2(qh[1], ka.y, s);
            s = dot2(qh[2], ka.z, s);
            s = dot2(qh[3], ka.w, s);
            s = dot2(qh[4], kb.x, s);
            s = dot2(qh[5], kb.y, s);
            s = dot2(qh[6], kb.z, s);
            s = dot2(qh[7], kb.w, s);
            sc[di * 5 + dj] = s;
        }
    }
    {
        float s = q[0] * q[0];
#pragma unroll
        for (int d = 1; d < Dn; ++d) s = fmaf(q[d], q[d], s);
        sc[25] = s;
    }

    // ---- per-head softmax in registers ----
    float mx = sc[0];
#pragma unroll
    for (int i = 1; i < NS; ++i) mx = fmaxf(mx, sc[i]);
    float ssum = 0.f;
#pragma unroll
    for (int i = 0; i < NS; ++i) { sc[i] = __expf(sc[i] - mx); ssum += sc[i]; }
    const float inv = 1.0f / ssum;
#pragma unroll
    for (int i = 0; i < NS; ++i) sc[i] *= inv;

    // ---- head-mean via LDS (reuse sK as f16 [4][64][28]) ----
    __syncthreads();                         // all k reads complete
    {
        unsigned int* myrow = sK + (wv * 64 + lane) * 14;
#pragma unroll
        for (int j = 0; j < 13; ++j) myrow[j] = pkf16(sc[2 * j], sc[2 * j + 1]);
    }
    __syncthreads();

    // ---- combine 4 heads + coalesced store (208-float contiguous runs) ----
    const unsigned short* sA = (const unsigned short*)sK;
    const size_t obase = (((size_t)b * Hn + y0) * Wn + x0) * NS;
    for (int idx = tid; idx < TILE * TILE * NS; idx += 256) {
        const int r  = idx / (TILE * NS);
        const int t  = idx - r * (TILE * NS);
        const int c  = t / NS;
        const int i  = t - c * NS;
        const int px = r * TILE + c;
        float acc = 0.f;
#pragma unroll
        for (int h = 0; h < 4; ++h)
            acc += (float)__builtin_bit_cast(_Float16, sA[(h * 64 + px) * 28 + i]);
        out[obase + (size_t)r * (Wn * NS) + t] = 0.25f * acc;
    }
}

extern "C" void kernel_launch(void* const* d_in, const int* in_sizes, int n_in,
                              void* d_out, int out_size, void* d_ws, size_t ws_size,
                              hipStream_t stream) {
    (void)in_sizes; (void)n_in; (void)ws_size; (void)out_size;
    const float* mainp = (const float*)d_in[0];
    const float* refp  = (const float*)d_in[1];
    const float* Wm    = (const float*)d_in[2];
    const float* Wr    = (const float*)d_in[3];
    unsigned int* wpk  = (unsigned int*)d_ws;        // 16 KB packed weights
    float* out = (float*)d_out;
    pack_weights<<<16, 256, 0, stream>>>(Wm, Wr, wpk);
    dim3 grid(Wn / TILE, Hn / TILE, Bn);   // 16 x 16 x 8 = 2048 blocks
    local_attn_fused<<<grid, 256, 0, stream>>>(mainp, refp, wpk, out);
}

// Round 5
// 57.727 us; speedup vs baseline: 1.9425x; 1.2090x over previous
//
#include <hip/hip_runtime.h>

#define Bn 8
#define Hn 128
#define Wn 128
#define Cn 64
#define Dn 16
#define NS 26            // 5*5 neighbors + self
#define TILE 8           // 8x8 pixel tile per score block
#define HALO 12          // TILE + 2*2
#define NHALO (HALO * HALO)   // 144
#define PXW 36           // u32 words per halo px in LDS: 4 heads*8 + 4 pad
#define NPX (Bn * Hn * Wn)    // 131072
#define NPX8 (NPX * 8)        // u32 per head-plane of packed f16 q or k

// ws layout (bytes): [0,16K) packed weights | [16K, +16.78M) q | then k
#define WS_WP_U32   4096
#define WS_Q_OFF    4096
#define WS_K_OFF    (WS_Q_OFF + 4 * NPX8)
#define WS_NEEDED   ((size_t)(WS_K_OFF + 4 * NPX8) * 4)

typedef _Float16 h2 __attribute__((ext_vector_type(2)));

__device__ __forceinline__ unsigned int pkf16(float a, float b) {
    return __builtin_bit_cast(unsigned int, __builtin_amdgcn_cvt_pkrtz(a, b));
}
__device__ __forceinline__ float dot2(unsigned int a, unsigned int b, float c) {
    return __builtin_amdgcn_fdot2(__builtin_bit_cast(h2, a),
                                  __builtin_bit_cast(h2, b), c, false);
}

// ---- pack W into c-pair-major f16x2: wp[t][h][m][d], m = c/2 ----
__global__ void pack_weights(const float* __restrict__ Wm,
                             const float* __restrict__ Wr,
                             unsigned int* __restrict__ wp) {
    const int idx = blockIdx.x * 256 + threadIdx.x;
    if (idx < 2 * 4 * 32 * Dn) {
        const int t = idx >> 11;
        const int r = idx & 2047;
        const int h = r >> 9;
        const int m = (r >> 4) & 31;
        const int d = r & 15;
        const float* W = t ? Wr : Wm;
        wp[idx] = pkf16(W[h * (Cn * Dn) + (2 * m) * Dn + d],
                        W[h * (Cn * Dn) + (2 * m + 1) * Dn + d]);
    }
}

__device__ __forceinline__ void proj16(const float4* sIn, int lane,
                                       const unsigned int* wh, float* acc) {
#pragma unroll
    for (int c4 = 0; c4 < 16; ++c4) {
        const float4 v = sIn[lane * 17 + c4];
        const unsigned int a01 = pkf16(v.x, v.y);
        const unsigned int a23 = pkf16(v.z, v.w);
        const unsigned int* w0 = wh + (2 * c4) * Dn;
        const unsigned int* w1 = wh + (2 * c4 + 1) * Dn;
#pragma unroll
        for (int d = 0; d < Dn; ++d) acc[d] = dot2(a01, w0[d], acc[d]);
#pragma unroll
        for (int d = 0; d < Dn; ++d) acc[d] = dot2(a23, w1[d], acc[d]);
    }
}

// ---- pass 1: q,k projections for every px-head, exactly once ----
// 256 thr = 64 px x 4 waves (wave = head). Input tile staged in LDS with
// 17-float4 row stride (optimal 8-cycle b128 pattern). Output f16 packed,
// [head][px][8 u32] -> lane-stride 32B stores, coalesced.
__global__ __launch_bounds__(256, 3)
void proj_qk(const float* __restrict__ mainp,
             const float* __restrict__ refp,
             const unsigned int* __restrict__ wp,
             unsigned int* __restrict__ wsQ,
             unsigned int* __restrict__ wsK)
{
    __shared__ float4 sIn[64 * 17];   // 17408 B

    const int tid  = threadIdx.x;
    const int lane = tid & 63;
    const int wv   = tid >> 6;
    const int head = __builtin_amdgcn_readfirstlane(wv);
    const int pxbase = blockIdx.x * 64;

    const unsigned int* wmh = wp + head * (32 * Dn);
    const unsigned int* wrh = wp + 2048 + head * (32 * Dn);

    // stage main tile (64 px x 64 ch = 16 KB), coalesced
    const float4* mp4 = (const float4*)mainp + (size_t)pxbase * 16;
#pragma unroll
    for (int t = 0; t < 4; ++t) {
        const int idx = t * 256 + tid;
        sIn[(idx >> 4) * 17 + (idx & 15)] = mp4[idx];
    }
    __syncthreads();

    float acc[Dn];
#pragma unroll
    for (int d = 0; d < Dn; ++d) acc[d] = 0.f;
    proj16(sIn, lane, wmh, acc);
    {
        unsigned int* dst = wsQ + (size_t)head * NPX8 + (size_t)(pxbase + lane) * 8;
        *(uint4*)(dst)     = make_uint4(pkf16(acc[0], acc[1]),  pkf16(acc[2], acc[3]),
                                        pkf16(acc[4], acc[5]),  pkf16(acc[6], acc[7]));
        *(uint4*)(dst + 4) = make_uint4(pkf16(acc[8], acc[9]),  pkf16(acc[10], acc[11]),
                                        pkf16(acc[12], acc[13]), pkf16(acc[14], acc[15]));
    }

    __syncthreads();   // done reading main tile
    const float4* rp4 = (const float4*)refp + (size_t)pxbase * 16;
#pragma unroll
    for (int t = 0; t < 4; ++t) {
        const int idx = t * 256 + tid;
        sIn[(idx >> 4) * 17 + (idx & 15)] = rp4[idx];
    }
    __syncthreads();

#pragma unroll
    for (int d = 0; d < Dn; ++d) acc[d] = 0.f;
    proj16(sIn, lane, wrh, acc);
    {
        unsigned int* dst = wsK + (size_t)head * NPX8 + (size_t)(pxbase + lane) * 8;
        *(uint4*)(dst)     = make_uint4(pkf16(acc[0], acc[1]),  pkf16(acc[2], acc[3]),
                                        pkf16(acc[4], acc[5]),  pkf16(acc[6], acc[7]));
        *(uint4*)(dst + 4) = make_uint4(pkf16(acc[8], acc[9]),  pkf16(acc[10], acc[11]),
                                        pkf16(acc[12], acc[13]), pkf16(acc[14], acc[15]));
    }
}

// ---- pass 2: scores + softmax + head-mean. Staging is a pure copy. ----
__global__ __launch_bounds__(256, 3)
void attn_scores(const unsigned int* __restrict__ wsQ,
                 const unsigned int* __restrict__ wsK,
                 float* __restrict__ out)
{
    __shared__ unsigned int sK[NHALO * PXW];   // 20736 B

    const int tid  = threadIdx.x;
    const int lane = tid & 63;
    const int wv   = tid >> 6;
    const int head = __builtin_amdgcn_readfirstlane(wv);
    const int b    = blockIdx.z;
    const int y0   = blockIdx.y * TILE;
    const int x0   = blockIdx.x * TILE;

    // stage my head's k halo (zero for SAME-pad oob)
    const unsigned int* wk = wsK + (size_t)head * NPX8;
    for (int p = lane; p < NHALO; p += 64) {
        const int hr = p / HALO;
        const int hc = p - hr * HALO;
        const int gy = y0 - 2 + hr;
        const int gx = x0 - 2 + hc;
        uint4 A = make_uint4(0, 0, 0, 0), Bv = make_uint4(0, 0, 0, 0);
        if ((unsigned)gy < (unsigned)Hn && (unsigned)gx < (unsigned)Wn) {
            const unsigned int* s = wk + (size_t)((b * Hn + gy) * Wn + gx) * 8;
            A  = *(const uint4*)(s);
            Bv = *(const uint4*)(s + 4);
        }
        unsigned int* d = sK + p * PXW + head * 8;
        *(uint4*)(d)     = A;
        *(uint4*)(d + 4) = Bv;
    }

    // my q (pre-barrier: overlaps staging)
    const int pr = lane >> 3;
    const int pc = lane & 7;
    const int px = (b * Hn + (y0 + pr)) * Wn + (x0 + pc);
    const unsigned int* qp = wsQ + (size_t)head * NPX8 + (size_t)px * 8;
    const uint4 qa = *(const uint4*)(qp);
    const uint4 qb = *(const uint4*)(qp + 4);
    const unsigned int qh[8] = {qa.x, qa.y, qa.z, qa.w, qb.x, qb.y, qb.z, qb.w};

    __syncthreads();

    // 25 neighbor scores: explicit next-neighbor prefetch + 2 accumulators
    float sc[NS];
    const int base = head * 8;
    uint4 ka = *(const uint4*)(sK + ((pr) * HALO + (pc)) * PXW + base);
    uint4 kb = *(const uint4*)(sK + ((pr) * HALO + (pc)) * PXW + base + 4);
#pragma unroll
    for (int j = 0; j < 25; ++j) {
        uint4 na = ka, nb = kb;
        if (j < 24) {
            const int jn = j + 1;
            const int di = jn / 5;
            const int dj = jn - di * 5;
            const int hn = (pr + di) * HALO + (pc + dj);
            na = *(const uint4*)(sK + hn * PXW + base);
            nb = *(const uint4*)(sK + hn * PXW + base + 4);
        }
        float s0 = dot2(qh[0], ka.x, 0.f);
        float s1 = dot2(qh[1], ka.y, 0.f);
        s0 = dot2(qh[2], ka.z, s0);
        s1 = dot2(qh[3], ka.w, s1);
        s0 = dot2(qh[4], kb.x, s0);
        s1 = dot2(qh[5], kb.y, s1);
        s0 = dot2(qh[6], kb.z, s0);
        s1 = dot2(qh[7], kb.w, s1);
        sc[j] = s0 + s1;
        ka = na; kb = nb;
    }
    {   // self score q.q (f16 q, consistent with stored q)
        float s0 = dot2(qh[0], qh[0], 0.f);
        float s1 = dot2(qh[1], qh[1], 0.f);
        s0 = dot2(qh[2], qh[2], s0);
        s1 = dot2(qh[3], qh[3], s1);
        s0 = dot2(qh[4], qh[4], s0);
        s1 = dot2(qh[5], qh[5], s1);
        s0 = dot2(qh[6], qh[6], s0);
        s1 = dot2(qh[7], qh[7], s1);
        sc[25] = s0 + s1;
    }

    // softmax
    float mx = sc[0];
#pragma unroll
    for (int i = 1; i < NS; ++i) mx = fmaxf(mx, sc[i]);
    float ssum = 0.f;
#pragma unroll
    for (int i = 0; i < NS; ++i) { sc[i] = __expf(sc[i] - mx); ssum += sc[i]; }
    const float inv = 1.0f / ssum;
#pragma unroll
    for (int i = 0; i < NS; ++i) sc[i] *= inv;

    // head-mean via LDS (reuse sK as f16 rows, u32 stride 14)
    __syncthreads();
    {
        unsigned int* myrow = sK + (wv * 64 + lane) * 14;
#pragma unroll
        for (int j = 0; j < 13; ++j) myrow[j] = pkf16(sc[2 * j], sc[2 * j + 1]);
    }
    __syncthreads();

    const unsigned short* sA = (const unsigned short*)sK;
    const size_t obase = (((size_t)b * Hn + y0) * Wn + x0) * NS;
    for (int idx = tid; idx < TILE * TILE * NS; idx += 256) {
        const int r   = idx / (TILE * NS);
        const int t   = idx - r * (TILE * NS);
        const int c   = t / NS;
        const int i   = t - c * NS;
        const int ppx = r * TILE + c;
        float acc = 0.f;
#pragma unroll
        for (int h = 0; h < 4; ++h)
            acc += (float)__builtin_bit_cast(_Float16, sA[(h * 64 + ppx) * 28 + i]);
        out[obase + (size_t)r * (Wn * NS) + t] = 0.25f * acc;
    }
}

// ================= fallback: R4 monolithic (needs only 16 KB ws) ==========
__global__ __launch_bounds__(256, 4)
void local_attn_fused_r4(const float* __restrict__ mainp,
                         const float* __restrict__ refp,
                         const unsigned int* __restrict__ wp,
                         float* __restrict__ out)
{
    __shared__ unsigned int sK[NHALO * PXW];
    const int tid  = threadIdx.x;
    const int lane = tid & 63;
    const int wv   = tid >> 6;
    const int head = __builtin_amdgcn_readfirstlane(wv);
    const int b    = blockIdx.z;
    const int y0   = blockIdx.y * TILE;
    const int x0   = blockIdx.x * TILE;
    const unsigned int* wmh = wp + head * (32 * Dn);
    const unsigned int* wrh = wp + 2048 + head * (32 * Dn);
    for (int p = lane; p < NHALO; p += 64) {
        const int hr = p / HALO;
        const int hc = p - hr * HALO;
        const int gy = y0 - 2 + hr;
        const int gx = x0 - 2 + hc;
        float acc[Dn];
#pragma unroll
        for (int d = 0; d < Dn; ++d) acc[d] = 0.f;
        if ((unsigned)gy < (unsigned)Hn && (unsigned)gx < (unsigned)Wn) {
            const float4* rp4 = (const float4*)(refp + (((size_t)b * Hn + gy) * Wn + gx) * Cn);
#pragma unroll
            for (int c4 = 0; c4 < Cn / 4; ++c4) {
                const float4 rv = rp4[c4];
                const unsigned int r01 = pkf16(rv.x, rv.y);
                const unsigned int r23 = pkf16(rv.z, rv.w);
                const unsigned int* w0 = wrh + (2 * c4) * Dn;
                const unsigned int* w1 = wrh + (2 * c4 + 1) * Dn;
#pragma unroll
                for (int d = 0; d < Dn; ++d) acc[d] = dot2(r01, w0[d], acc[d]);
#pragma unroll
                for (int d = 0; d < Dn; ++d) acc[d] = dot2(r23, w1[d], acc[d]);
            }
        }
        unsigned int pk[8];
#pragma unroll
        for (int j = 0; j < 8; ++j) pk[j] = pkf16(acc[2 * j], acc[2 * j + 1]);
        unsigned int* dst = sK + p * PXW + head * 8;
        *(uint4*)(dst)     = make_uint4(pk[0], pk[1], pk[2], pk[3]);
        *(uint4*)(dst + 4) = make_uint4(pk[4], pk[5], pk[6], pk[7]);
    }
    const int pr = lane >> 3;
    const int pc = lane & 7;
    const float4* mp4 = (const float4*)(mainp + (((size_t)b * Hn + (y0 + pr)) * Wn + (x0 + pc)) * Cn);
    float q[Dn];
#pragma unroll
    for (int d = 0; d < Dn; ++d) q[d] = 0.f;
#pragma unroll
    for (int c4 = 0; c4 < Cn / 4; ++c4) {
        const float4 mv = mp4[c4];
        const unsigned int m01 = pkf16(mv.x, mv.y);
        const unsigned int m23 = pkf16(mv.z, mv.w);
        const unsigned int* w0 = wmh + (2 * c4) * Dn;
        const unsigned int* w1 = wmh + (2 * c4 + 1) * Dn;
#pragma unroll
        for (int d = 0; d < Dn; ++d) q[d] = dot2(m01, w0[d], q[d]);
#pragma unroll
        for (int d = 0; d < Dn; ++d) q[d] = dot2(m23, w1[d], q[d]);
    }
    unsigned int qh[8];
#pragma unroll
    for (int j = 0; j < 8; ++j) qh[j] = pkf16(q[2 * j], q[2 * j + 1]);
    __syncthreads();
    float sc[NS];
#pragma unroll
    for (int di = 0; di < 5; ++di) {
#pragma unroll
        for (int dj = 0; dj < 5; ++dj) {
            const int h = (pr + di) * HALO + (pc + dj);
            const unsigned int* src = sK + h * PXW + head * 8;
            const uint4 ka = *(const uint4*)(src);
            const uint4 kb = *(const uint4*)(src + 4);
            float s;
            s = dot2(qh[0], ka.x, 0.f);
            s = dot2(qh[1], ka.y, s);
            s = dot2(qh[2], ka.z, s);
            s = dot2(qh[3], ka.w, s);
            s = dot2(qh[4], kb.x, s);
            s = dot2(qh[5], kb.y, s);
            s = dot2(qh[6], kb.z, s);
            s = dot2(qh[7], kb.w, s);
            sc[di * 5 + dj] = s;
        }
    }
    {
        float s = q[0] * q[0];
#pragma unroll
        for (int d = 1; d < Dn; ++d) s = fmaf(q[d], q[d], s);
        sc[25] = s;
    }
    float mx = sc[0];
#pragma unroll
    for (int i = 1; i < NS; ++i) mx = fmaxf(mx, sc[i]);
    float ssum = 0.f;
#pragma unroll
    for (int i = 0; i < NS; ++i) { sc[i] = __expf(sc[i] - mx); ssum += sc[i]; }
    const float inv = 1.0f / ssum;
#pragma unroll
    for (int i = 0; i < NS; ++i) sc[i] *= inv;
    __syncthreads();
    {
        unsigned int* myrow = sK + (wv * 64 + lane) * 14;
#pragma unroll
        for (int j = 0; j < 13; ++j) myrow[j] = pkf16(sc[2 * j], sc[2 * j + 1]);
    }
    __syncthreads();
    const unsigned short* sA = (const unsigned short*)sK;
    const size_t obase = (((size_t)b * Hn + y0) * Wn + x0) * NS;
    for (int idx = tid; idx < TILE * TILE * NS; idx += 256) {
        const int r   = idx / (TILE * NS);
        const int t   = idx - r * (TILE * NS);
        const int c   = t / NS;
        const int i   = t - c * NS;
        const int ppx = r * TILE + c;
        float acc = 0.f;
#pragma unroll
        for (int h = 0; h < 4; ++h)
            acc += (float)__builtin_bit_cast(_Float16, sA[(h * 64 + ppx) * 28 + i]);
        out[obase + (size_t)r * (Wn * NS) + t] = 0.25f * acc;
    }
}

extern "C" void kernel_launch(void* const* d_in, const int* in_sizes, int n_in,
                              void* d_out, int out_size, void* d_ws, size_t ws_size,
                              hipStream_t stream) {
    (void)in_sizes; (void)n_in; (void)out_size;
    const float* mainp = (const float*)d_in[0];
    const float* refp  = (const float*)d_in[1];
    const float* Wm    = (const float*)d_in[2];
    const float* Wr    = (const float*)d_in[3];
    unsigned int* wpk  = (unsigned int*)d_ws;
    float* out = (float*)d_out;

    pack_weights<<<16, 256, 0, stream>>>(Wm, Wr, wpk);
    dim3 grid2(Wn / TILE, Hn / TILE, Bn);          // 16 x 16 x 8
    if (ws_size >= WS_NEEDED) {
        unsigned int* wsQ = wpk + WS_Q_OFF;
        unsigned int* wsK = wpk + WS_K_OFF;
        proj_qk<<<NPX / 64, 256, 0, stream>>>(mainp, refp, wpk, wsQ, wsK);
        attn_scores<<<grid2, 256, 0, stream>>>(wsQ, wsK, out);
    } else {
        local_attn_fused_r4<<<grid2, 256, 0, stream>>>(mainp, refp, wpk, out);
    }
}